// Round 1
// baseline (3884.629 us; speedup 1.0000x reference)
//
#include <hip/hip_runtime.h>

// Echo-state RNN, B=32, T=2048, NH=512, NI=NO=1.
// Key facts: W_hh is ~90% exact zeros (bernoulli 0.1 mask). Batches are fully
// independent sequential chains. Strategy: one workgroup (one CU) per batch,
// thread j owns hidden unit j; sparse W_hh rows live in REGISTERS (padded to
// 88 entries), tanh(h) double-buffered in LDS (1 barrier/step), z via wave
// shuffle + cross-wave LDS reduce. A preprocessing kernel builds the padded
// sparse format in d_ws (entry-major so the main kernel's loads coalesce).

#define NH  512
#define TT  2048
#define BB  32
#define PAD 88          // max nnz/row: mean 51.2, sigma 6.8 -> 88 is ~5.4 sigma
#define PADH (PAD/2)

// ---------------------------------------------------------------------------
// Preprocess: wave-per-row ballot compaction of W_hh into padded sparse form.
// vals[e*NH + row] = value of e-th nonzero of row; offs[e*NH + row] = column.
// Padding entries get val=0, off=0 (harmless fma with t[0]).
// ---------------------------------------------------------------------------
__global__ __launch_bounds__(512) void build_sparse(
    const float* __restrict__ Whh, float* __restrict__ vals,
    unsigned* __restrict__ offs) {
  const int wib  = threadIdx.x >> 6;   // wave in block (0..7)
  const int lane = threadIdx.x & 63;
  const int row  = blockIdx.x * 8 + wib;
  if (row >= NH) return;
  const float* wrow = Whh + (size_t)row * NH;
  int cnt = 0;
  for (int c = 0; c < NH / 64; ++c) {
    float w = wrow[c * 64 + lane];
    unsigned long long m = __ballot(w != 0.0f);
    if (w != 0.0f) {
      int pos = cnt + __popcll(m & ((1ull << lane) - 1ull));
      if (pos < PAD) {
        vals[pos * NH + row] = w;
        offs[pos * NH + row] = (unsigned)(c * 64 + lane);
      }
    }
    cnt += __popcll(m);
  }
  // pad remainder in parallel across the wave
  for (int e = cnt + lane; e < PAD; e += 64) {
    vals[e * NH + row] = 0.0f;
    offs[e * NH + row] = 0u;
  }
}

// ---------------------------------------------------------------------------
// Main: one block per batch. 512 threads = 8 waves. 2048 sequential steps.
// ---------------------------------------------------------------------------
__global__ __launch_bounds__(512, 2) void esn_steps(
    const float* __restrict__ x,   const float* __restrict__ h0,
    const float* __restrict__ Wih, const float* __restrict__ Whz,
    const float* __restrict__ Wzh, const float* __restrict__ vals,
    const unsigned* __restrict__ offs, float* __restrict__ out) {
  __shared__ float t_lds[2][NH];   // tanh(h), double-buffered
  __shared__ float x_lds[TT];      // this batch's input row (8 KB)
  __shared__ float red[2][8];      // cross-wave partials for z

  const int j    = threadIdx.x;    // hidden unit owned by this thread
  const int b    = blockIdx.x;     // batch
  const int lane = j & 63;
  const int wid  = j >> 6;

  // stage x row into LDS (coalesced, 4 iters)
  for (int i = j; i < TT; i += NH) x_lds[i] = x[(size_t)b * TT + i];

  // pull this row's sparse entries into registers (static indices only)
  float    wval[PAD];
  unsigned woff[PADH];             // two u16 column indices per reg
  #pragma unroll
  for (int e = 0; e < PAD; ++e) wval[e] = vals[e * NH + j];
  #pragma unroll
  for (int ep = 0; ep < PADH; ++ep) {
    unsigned lo = offs[(2 * ep) * NH + j];
    unsigned hi = offs[(2 * ep + 1) * NH + j];
    woff[ep] = lo | (hi << 16);
  }

  const float w_ih = Wih[j];
  const float w_hz = Whz[j];
  const float w_zh = Wzh[j];
  float h = h0[(size_t)b * NH + j];

  float* oz = out + (size_t)b * TT;                       // z region [B,T,1]
  float* oh = out + (size_t)BB * TT + (size_t)b * TT * NH; // h region [B,T,NH]

  // ---- init: t[0] = tanh(h0); z_prev = sum(tanh(h0) * Whz) ----
  float th0 = tanhf(h);
  t_lds[0][j] = th0;
  float pz = th0 * w_hz;
  #pragma unroll
  for (int o = 32; o > 0; o >>= 1) pz += __shfl_xor(pz, o);
  if (lane == 0) red[0][wid] = pz;
  __syncthreads();
  float z_prev = 0.0f;
  #pragma unroll
  for (int r = 0; r < 8; ++r) z_prev += red[0][r];

  // ---- 2048 sequential steps, one barrier each ----
  for (int s = 0; s < TT; ++s) {
    const int rd = s & 1, wr = rd ^ 1;

    // sparse dot: sum_k W_hh[j,k] * tanh(h_prev[k]); 4 accumulator chains
    float d0 = 0.f, d1 = 0.f, d2 = 0.f, d3 = 0.f;
    #pragma unroll
    for (int e = 0; e < PAD; e += 4) {
      unsigned p0 = woff[e >> 1];
      unsigned p1 = woff[(e >> 1) + 1];
      d0 = fmaf(wval[e],     t_lds[rd][p0 & 0xFFFFu], d0);
      d1 = fmaf(wval[e + 1], t_lds[rd][p0 >> 16],      d1);
      d2 = fmaf(wval[e + 2], t_lds[rd][p1 & 0xFFFFu], d2);
      d3 = fmaf(wval[e + 3], t_lds[rd][p1 >> 16],      d3);
    }
    float dot = (d0 + d1) + (d2 + d3);

    float xp   = x_lds[s] * w_ih;
    float dhdt = ((dot - h) + xp) + z_prev * w_zh;
    float hn   = h + 0.1f * dhdt;      // alpha = dt/tau = 0.1
    float thn  = tanhf(hn);

    t_lds[wr][j] = thn;                 // next step's operand (other buffer)
    oh[s * NH + j] = hn;                // h output, coalesced

    float pzs = thn * w_hz;             // z_t reduction
    #pragma unroll
    for (int o = 32; o > 0; o >>= 1) pzs += __shfl_xor(pzs, o);
    if (lane == 0) red[wr][wid] = pzs;

    __syncthreads();

    float z = 0.0f;
    #pragma unroll
    for (int r = 0; r < 8; ++r) z += red[wr][r];
    if (j == 0) oz[s] = z;

    z_prev = z;
    h = hn;
  }
}

// ---------------------------------------------------------------------------
extern "C" void kernel_launch(void* const* d_in, const int* in_sizes, int n_in,
                              void* d_out, int out_size, void* d_ws,
                              size_t ws_size, hipStream_t stream) {
  const float* x   = (const float*)d_in[0];
  const float* h0  = (const float*)d_in[1];
  const float* Wih = (const float*)d_in[2];
  const float* Whh = (const float*)d_in[3];
  const float* Whz = (const float*)d_in[4];
  const float* Wzh = (const float*)d_in[5];
  float* out = (float*)d_out;

  float*    vals = (float*)d_ws;                 // PAD*NH f32   = 180 KB
  unsigned* offs = (unsigned*)(vals + PAD * NH); // PAD*NH u32   = 180 KB

  hipLaunchKernelGGL(build_sparse, dim3(NH / 8), dim3(512), 0, stream,
                     Whh, vals, offs);
  hipLaunchKernelGGL(esn_steps, dim3(BB), dim3(512), 0, stream,
                     x, h0, Wih, Whz, Wzh, vals, offs, out);
}